// Round 1
// baseline (39.885 us; speedup 1.0000x reference)
//
#include <hip/hip_runtime.h>

#define H 512
#define W 512
#define N (H * W)
#define INF_SQ 524289.0f  // H*H + W*W + 1, matches reference INF

__global__ void init_ws_k(unsigned int* s) {
    s[0] = 0u;  // max(masks) bits
    s[1] = 0u;  // max(dis) bits
}

__global__ void max_mask_k(const float* __restrict__ masks, unsigned int* s) {
    int tid = blockIdx.x * blockDim.x + threadIdx.x;
    int stride = gridDim.x * blockDim.x;
    float m = 0.0f;
    for (int i = tid; i < N; i += stride) m = fmaxf(m, masks[i]);
    for (int off = 32; off > 0; off >>= 1) m = fmaxf(m, __shfl_down(m, off, 64));
    __shared__ float sm[4];
    int lane = threadIdx.x & 63, wid = threadIdx.x >> 6;
    if (lane == 0) sm[wid] = m;
    __syncthreads();
    if (threadIdx.x == 0) {
        int nw = blockDim.x >> 6;
        for (int i = 1; i < nw; i++) m = fmaxf(m, sm[i]);
        atomicMax(s, __float_as_uint(m));
    }
}

// One block per column c: d1[i][c] = min_j (i-j)^2 + f[j][c], f in {0, INF}
__global__ void col_pass_k(const float* __restrict__ masks, float* __restrict__ d1) {
    int c = blockIdx.x;
    int t = threadIdx.x;  // 512 threads = rows
    __shared__ float sf[H];
    sf[t] = (masks[t * W + c] == 0.0f) ? 0.0f : INF_SQ;
    __syncthreads();
    float m = 1e30f;
    float dl = (float)t;
#pragma unroll 8
    for (int j = 0; j < H; ++j) {
        m = fminf(m, fmaf(dl, dl, sf[j]));
        dl -= 1.0f;
    }
    d1[t * W + c] = m;
}

// One block per row h: d2[h][k] = min_l (k-l)^2 + d1[h][l]; dis = sqrt(d2)
__global__ void row_pass_k(const float* __restrict__ d1, float* __restrict__ dis,
                           unsigned int* s) {
    int h = blockIdx.x;
    int k = threadIdx.x;  // 512 threads = cols
    __shared__ float sr[W];
    sr[k] = d1[h * W + k];
    __syncthreads();
    float m = 1e30f;
    float dl = (float)k;
#pragma unroll 8
    for (int l = 0; l < W; ++l) {
        m = fminf(m, fmaf(dl, dl, sr[l]));
        dl -= 1.0f;
    }
    float d = sqrtf(m);
    dis[h * W + k] = d;
    // block max reduce for max(dis)
    for (int off = 32; off > 0; off >>= 1) d = fmaxf(d, __shfl_down(d, off, 64));
    __shared__ float sm[8];
    int lane = k & 63, wid = k >> 6;
    if (lane == 0) sm[wid] = d;
    __syncthreads();
    if (k == 0) {
        for (int i = 1; i < 8; i++) d = fmaxf(d, sm[i]);
        atomicMax(s + 1, __float_as_uint(d));
    }
}

__global__ void finalize_k(const float* __restrict__ masks, float* __restrict__ out,
                           const unsigned int* __restrict__ s) {
    int i = blockIdx.x * blockDim.x + threadIdx.x;
    if (i >= N) return;
    float maxm = __uint_as_float(s[0]);
    float maxd = __uint_as_float(s[1]);
    float d = out[i];           // dis written by row_pass
    float sk = d / maxd;
    float b = masks[i] / maxm - sk;
    out[i] = sk;        // skeleton
    out[N + i] = b;     // boundary (overwrites d1 scratch)
}

extern "C" void kernel_launch(void* const* d_in, const int* in_sizes, int n_in,
                              void* d_out, int out_size, void* d_ws, size_t ws_size,
                              hipStream_t stream) {
    const float* masks = (const float*)d_in[0];
    float* out = (float*)d_out;
    unsigned int* s = (unsigned int*)d_ws;
    float* d1 = out + N;  // stash d1 in the boundary half of d_out

    hipLaunchKernelGGL(init_ws_k, dim3(1), dim3(1), 0, stream, s);
    hipLaunchKernelGGL(max_mask_k, dim3(256), dim3(256), 0, stream, masks, s);
    hipLaunchKernelGGL(col_pass_k, dim3(W), dim3(H), 0, stream, masks, d1);
    hipLaunchKernelGGL(row_pass_k, dim3(H), dim3(W), 0, stream, d1, out, s);
    hipLaunchKernelGGL(finalize_k, dim3((N + 255) / 256), dim3(256), 0, stream, masks, out, s);
}

// Round 2
// 24.112 us; speedup vs baseline: 1.6541x; 1.6541x over previous
//
#include <hip/hip_runtime.h>

#define H 512
#define W 512
#define N (H * W)
#define INF_SQ 524289.0f  // H*H + W*W + 1, matches reference INF

// K1: one block per column c. Exact d1 via nearest-zero scan:
//   d1[i][c] = nd^2 if a zero exists (nd = nearest zero distance), else INF_SQ.
// Also emits colmax[c] = max over rows of masks[.][c] (no atomics).
__global__ void colscan_k(const float* __restrict__ masks, float* __restrict__ d1,
                          float* __restrict__ colmax) {
    const int c = blockIdx.x;
    const int t = threadIdx.x;  // row

    __shared__ int A[H];   // prefix max of zero-indices
    __shared__ int B[H];   // suffix min of zero-indices
    __shared__ float mx[8];

    const float v = masks[t * W + c];
    const bool z = (v == 0.0f);
    A[t] = z ? t : -100000;
    B[t] = z ? t : 100000;

    // per-column max of masks (wave shuffle reduce, width 64)
    float m = v;
    for (int off = 32; off > 0; off >>= 1) m = fmaxf(m, __shfl_down(m, off, 64));
    if ((t & 63) == 0) mx[t >> 6] = m;
    __syncthreads();

    // Hillis-Steele: prefix-max (A) and suffix-min (B) simultaneously
    for (int off = 1; off < H; off <<= 1) {
        int a = (t >= off) ? A[t - off] : -100000;
        int b = (t + off < H) ? B[t + off] : 100000;
        __syncthreads();
        A[t] = max(A[t], a);
        B[t] = min(B[t], b);
        __syncthreads();
    }

    const int nd = min(t - A[t], B[t] - t);
    d1[t * W + c] = (nd <= H - 1) ? (float)(nd * nd) : INF_SQ;

    if (t == 0) {
        float q = mx[0];
        for (int i = 1; i < 8; i++) q = fmaxf(q, mx[i]);
        colmax[c] = q;
    }
}

// K2: one block per row h. Exact min-plus with parabola (brute force, 4 ILP chains).
//   dis[h][k] = sqrt(min_l (k-l)^2 + d1[h][l]); rowmax[h] = max_k dis[h][k].
__global__ void rowpass_k(const float* __restrict__ d1, float* __restrict__ dis,
                          float* __restrict__ rowmax) {
    const int h = blockIdx.x;
    const int k = threadIdx.x;  // col

    __shared__ float sr[W];
    __shared__ float sm[8];
    sr[k] = d1[h * W + k];
    __syncthreads();

    float m0 = 1e30f, m1 = 1e30f, m2 = 1e30f, m3 = 1e30f;
    float dl0 = (float)k, dl1 = (float)(k - 1), dl2 = (float)(k - 2), dl3 = (float)(k - 3);
#pragma unroll 4
    for (int l = 0; l < W; l += 4) {
        m0 = fminf(m0, fmaf(dl0, dl0, sr[l]));
        m1 = fminf(m1, fmaf(dl1, dl1, sr[l + 1]));
        m2 = fminf(m2, fmaf(dl2, dl2, sr[l + 2]));
        m3 = fminf(m3, fmaf(dl3, dl3, sr[l + 3]));
        dl0 -= 4.0f; dl1 -= 4.0f; dl2 -= 4.0f; dl3 -= 4.0f;
    }
    const float d = sqrtf(fminf(fminf(m0, m1), fminf(m2, m3)));
    dis[h * W + k] = d;

    // block max reduce -> rowmax[h]
    float r = d;
    for (int off = 32; off > 0; off >>= 1) r = fmaxf(r, __shfl_down(r, off, 64));
    if ((k & 63) == 0) sm[k >> 6] = r;
    __syncthreads();
    if (k == 0) {
        for (int i = 1; i < 8; i++) r = fmaxf(r, sm[i]);
        rowmax[h] = r;
    }
}

// K3: one block per row. Every block redundantly reduces the 512 colmax and
// 512 rowmax partials (L2-resident, trivial), then normalizes its row.
__global__ void finalize_k(const float* __restrict__ masks,
                           const float* __restrict__ colmax,
                           const float* __restrict__ rowmax,
                           float* __restrict__ out) {
    const int h = blockIdx.x;
    const int t = threadIdx.x;

    __shared__ float smc[8], smr[8];
    float cm = colmax[t];
    float rm = rowmax[t];
    for (int off = 32; off > 0; off >>= 1) {
        cm = fmaxf(cm, __shfl_down(cm, off, 64));
        rm = fmaxf(rm, __shfl_down(rm, off, 64));
    }
    if ((t & 63) == 0) { smc[t >> 6] = cm; smr[t >> 6] = rm; }
    __syncthreads();
    if (t == 0) {
        for (int i = 1; i < 8; i++) { cm = fmaxf(cm, smc[i]); rm = fmaxf(rm, smr[i]); }
        smc[0] = cm; smr[0] = rm;
    }
    __syncthreads();
    const float maxm = smc[0];
    const float maxd = smr[0];

    const int i = h * W + t;
    const float d = out[i];  // dis written by rowpass_k
    const float sk = d / maxd;
    const float b = masks[i] / maxm - sk;
    out[i] = sk;       // skeleton
    out[N + i] = b;    // boundary
}

extern "C" void kernel_launch(void* const* d_in, const int* in_sizes, int n_in,
                              void* d_out, int out_size, void* d_ws, size_t ws_size,
                              hipStream_t stream) {
    const float* masks = (const float*)d_in[0];
    float* out = (float*)d_out;
    float* d1 = (float*)d_ws;          // N floats
    float* colmax = d1 + N;            // 512 floats
    float* rowmax = colmax + W;        // 512 floats

    hipLaunchKernelGGL(colscan_k, dim3(W), dim3(H), 0, stream, masks, d1, colmax);
    hipLaunchKernelGGL(rowpass_k, dim3(H), dim3(W), 0, stream, d1, out, rowmax);
    hipLaunchKernelGGL(finalize_k, dim3(H), dim3(W), 0, stream, masks, colmax, rowmax, out);
}